// Round 12
// baseline (87.957 us; speedup 1.0000x reference)
//
#include <hip/hip_runtime.h>
#include <stdint.h>

typedef __attribute__((ext_vector_type(4)))  int   i32x4;
typedef __attribute__((ext_vector_type(8)))  int   i32x8;
typedef __attribute__((ext_vector_type(16))) float f32x16;

#define NB 8
#define NC 1024
#define NHW 3136
#define ROWB8 3200        // fp8 row stride: 3136 data + 64 zero pad = 25*128
#define NROWS 16384
#define NGRID 1280        // persistent norm grid (5-6 blocks/CU by LDS)

__device__ inline float sq4(float4 v){
  return fmaf(v.x,v.x, fmaf(v.y,v.y, fmaf(v.z,v.z, v.w*v.w)));
}

__device__ __forceinline__ void load_lds16(const void* g, void* l){
  __builtin_amdgcn_global_load_lds(
      (const __attribute__((address_space(1))) unsigned int*)g,
      (__attribute__((address_space(3))) unsigned int*)l,
      16, 0, 0);
}

// MX-scaled fp8 MFMA, both formats e4m3 (fmt=0), all block scales = 2^0.
__device__ __forceinline__ f32x16 MFS(i32x8 a, i32x8 b, f32x16 c){
  return __builtin_amdgcn_mfma_scale_f32_32x32x64_f8f6f4(
      a, b, c, 0, 0, 0, 0x7F7F7F7F, 0, 0x7F7F7F7F);
}

__device__ __forceinline__ i32x8 rdfrag(const char* base, int cLo, int cHi){
  i32x4 lo = *(const i32x4*)(base + cLo);
  i32x4 hi = *(const i32x4*)(base + cHi);
  return __builtin_shufflevector(lo, hi, 0,1,2,3,4,5,6,7);
}

__device__ __forceinline__ int cvt4(float4 v, float s){
  int pk = __builtin_amdgcn_cvt_pk_fp8_f32(v.x*s, v.y*s, 0,  0);
  pk     = __builtin_amdgcn_cvt_pk_fp8_f32(v.z*s, v.w*s, pk, 1);
  return pk;
}

#define BAR   __builtin_amdgcn_s_barrier()
#define LGKM0 asm volatile("s_waitcnt lgkmcnt(0)" ::: "memory")
#define LGKM8 asm volatile("s_waitcnt lgkmcnt(8)" ::: "memory")
#define VM6   asm volatile("s_waitcnt vmcnt(6)" ::: "memory")
#define VM4   asm volatile("s_waitcnt vmcnt(4)" ::: "memory")
#define VM0   asm volatile("s_waitcnt vmcnt(0)" ::: "memory")
#define SB0   __builtin_amdgcn_sched_barrier(0)
#define PRIO1 __builtin_amdgcn_s_setprio(1)
#define PRIO0 __builtin_amdgcn_s_setprio(0)

// ---------------- k_norm: persistent, double-buffered LDS-DMA pipeline ----
// 1280 blocks x 256 threads; each block grid-strides 12-13 rows. Two 13.3 KB
// LDS row buffers: while row i is reduced+cvt+stored from buf[cur], row i+1
// streams into buf[cur^1] via global_load_lds (gemm's T3/T4 counted-vmcnt
// pattern: every wave issues exactly 4 DMA/iter -- 3 full rounds + a padded
// tail round from all waves (lanes>=16 re-read row start into a dummy slot,
// never read back) -- then vmcnt(4) drains the CURRENT row's DMA (and the
// previous iteration's stores) while the NEXT row's 4 stay in flight).
// Raw s_barrier (no compiler vmcnt(0) drain). red[] WAR separated by >=2
// barriers. Output: e4m3 pre-scaled by 32, + 64 B zero pad.
__global__ __launch_bounds__(256) void k_norm(const float* __restrict__ s,
                                              const float* __restrict__ t,
                                              char* __restrict__ Sn,
                                              char* __restrict__ Tn,
                                              float* __restrict__ accbuf){
  __shared__ char nbuf[2][13312];      // 12544 data + 768 dummy-pad
  __shared__ float red[4];
  const int tid = threadIdx.x;
  const int l   = tid & 63;
  const int w   = tid >> 6;
  if (blockIdx.x == 0 && tid == 0){ accbuf[0] = 0.f; accbuf[1] = 0.f; }

#define NSRC(r) ((const char*)(((r) < 8192 ? s : t) + (size_t)((r) < 8192 ? (r) : (r)-8192) * NHW))
#define NDST(r) (((r) < 8192 ? Sn : Tn) + (size_t)((r) < 8192 ? (r) : (r)-8192) * ROWB8)
  // 4 uniform DMA issues per wave
#define NISSUE(gsrc, lbase) do{ \
    const char* _g = (gsrc); char* _l = (lbase); \
    load_lds16(_g + tid*16,         _l + tid*16); \
    load_lds16(_g + tid*16 +  4096, _l + tid*16 +  4096); \
    load_lds16(_g + tid*16 +  8192, _l + tid*16 +  8192); \
    load_lds16(_g + ((l < 16) ? 12288 + l*16 : l*16), _l + 12288 + l*16); \
  }while(0)

  int row = blockIdx.x;
  if (row >= NROWS) return;
  NISSUE(NSRC(row), nbuf[0]);                  // prologue: prime buf0
  int cur = 0;
  for (; row < NROWS; row += NGRID, cur ^= 1){
    int nrow = row + NGRID; if (nrow >= NROWS) nrow = row;   // junk re-DMA
    BAR;                                       // buf[cur^1] free (all waves)
    NISSUE(NSRC(nrow), nbuf[cur ^ 1]);
    VM4;                                       // drain this row's DMA + old stores
    BAR; SB0;                                  // buf[cur] valid block-wide

    const float4* B = (const float4*)nbuf[cur];
    float ssq = sq4(B[tid]) + sq4(B[tid+256]) + sq4(B[tid+512]);
    if (tid < 16) ssq += sq4(B[768 + tid]);
    #pragma unroll
    for (int off = 32; off; off >>= 1) ssq += __shfl_down(ssq, off);
    if ((tid & 63) == 0) red[w] = ssq;
    LGKM0; BAR;
    const float inv = 32.0f / fmaxf(sqrtf(red[0]+red[1]+red[2]+red[3]), 1e-12f);

    char* dst = NDST(row);
    *(int*)(dst + 4*tid)        = cvt4(B[tid],     inv);
    *(int*)(dst + 4*tid + 1024) = cvt4(B[tid+256], inv);
    *(int*)(dst + 4*tid + 2048) = cvt4(B[tid+512], inv);
    if (tid < 16)      *(int*)(dst + 3072 + 4*tid) = cvt4(B[768+tid], inv);
    else if (tid < 20) *(int4*)(dst + 3136 + 16*(tid-16)) = make_int4(0,0,0,0);
  }
  VM0;                                         // drain junk DMA before exit
#undef NISSUE
#undef NSRC
#undef NDST
}

// ---------------- 256x256 8-phase MX-fp8 GEMM, fused squared-sum -----------
// (byte-identical to the r4-verified schedule; r11's 4-phase merge regressed
// and is reverted.) K-tile = 128 fp8 = 128 B/row. 8 waves 2(M)x4(N);
// per-wave 128x64 out = 4 m-frags x 2 n-frags of 32x32, acc[8] f32x16.
// Dots scaled 2^10, squared sums 2^20, divided out in k_fin.

#define ISSUE(MAT, D, H, KT) do{ \
  const char* _g = ((MAT)? gB : gA) + (KT)*128 + (H)*(128*ROWB8); \
  char* _d = ldsw + (D)*65536 + (MAT)*32768 + (H)*16384; \
  load_lds16(_g,              _d); \
  load_lds16(_g + 64*ROWB8,   _d + 8192); \
}while(0)

#define RDA(D, MH) do{ \
  const char* _a = aRow + (D) + (MH)*8192; \
  af[0][0] = rdfrag(_a,        c00, c01); \
  af[0][1] = rdfrag(_a,        c10, c11); \
  af[1][0] = rdfrag(_a + 4096, c00, c01); \
  af[1][1] = rdfrag(_a + 4096, c10, c11); \
}while(0)

#define RDB(D, NH) do{ \
  const char* _b = bRow + (D) + (NH)*4096; \
  bf[NH][0] = rdfrag(_b, c00, c01); \
  bf[NH][1] = rdfrag(_b, c10, c11); \
}while(0)

#define MMQ(MH, NH) do{ \
  acc[((MH)*2+0)*2+(NH)] = MFS(af[0][0], bf[NH][0], acc[((MH)*2+0)*2+(NH)]); \
  acc[((MH)*2+1)*2+(NH)] = MFS(af[1][0], bf[NH][0], acc[((MH)*2+1)*2+(NH)]); \
  acc[((MH)*2+0)*2+(NH)] = MFS(af[0][1], bf[NH][1], acc[((MH)*2+0)*2+(NH)]); \
  acc[((MH)*2+1)*2+(NH)] = MFS(af[1][1], bf[NH][1], acc[((MH)*2+1)*2+(NH)]); \
}while(0)

__global__ __launch_bounds__(512,2) void k_gemm(const char* __restrict__ Sn,
                                                const char* __restrict__ Tn,
                                                float* __restrict__ accbuf){
  __shared__ char lds[131072];
  const int tid = threadIdx.x;
  const int l   = tid & 63;
  const int w   = tid >> 6;
  const int wr  = w >> 2;      // 0..1
  const int wc  = w & 3;       // 0..3

  const int b   = blockIdx.x & 7;    // batch -> XCD (208 = 8*26)
  const int idx = blockIdx.x >> 3;   // 0..25
  int tm, tn, which; float wgt;
  if (idx < 16){ which = 1; tm = idx >> 2; tn = idx & 3; wgt = 1.f; }
  else {
    int e = idx - 16; which = 0;
    if      (e < 4){ tm = 0; tn = e;   }
    else if (e < 7){ tm = 1; tn = e-3; }
    else if (e < 9){ tm = 2; tn = e-5; }
    else           { tm = 3; tn = 3;   }
    wgt = (tm == tn) ? 1.f : 2.f;
  }
  const char* Ab = (which ? Tn : Sn) + (size_t)b*(NC*ROWB8) + (size_t)tm*(256*ROWB8);
  const char* Bb = Sn                + (size_t)b*(NC*ROWB8) + (size_t)tn*(256*ROWB8);

  const int scol = ((l & 7) << 4) ^ ((l >> 3) << 4);
  const char* gA = Ab + (8*w + (l >> 3))*ROWB8 + scol;
  const char* gB = Bb + (8*w + (l >> 3))*ROWB8 + scol;
  char* ldsw = lds + w*1024;

  const int swz = (l & 7) << 4;
  const int cg  = 32*(l >> 5);
  const int c00 = ( cg           ) ^ swz;
  const int c01 = ( cg | 16      ) ^ swz;
  const int c10 = ( cg | 64      ) ^ swz;
  const int c11 = ( cg | 64 | 16 ) ^ swz;
  const char* aRow = lds +         (wr*128 + (l & 31))*128;
  const char* bRow = lds + 32768 + (wc*64  + (l & 31))*128;

  i32x8 af[2][2], bf[2][2];
  f32x16 acc[8];
  #pragma unroll
  for (int i = 0; i < 8; i++) acc[i] = (f32x16){};

  ISSUE(1,0,0,0); ISSUE(1,0,1,0); ISSUE(0,0,0,0); ISSUE(0,0,1,0);
  ISSUE(1,1,0,1); ISSUE(1,1,1,1); ISSUE(0,1,0,1);
  VM6; BAR;   // oldest 8 loads (= all of t0) landed

  for (int i = 0; i < 12; i++){
    const int t1 = 2*i + 1;
    const int t2 = 2*i + 2;
    int t3 = 2*i + 3; if (t3 > 24) t3 = 24;   // clamp keeps vmcnt uniform

    // ---- tile 2i (buf0) ----
    RDA(0,0); RDB(0,0);
    ISSUE(0,1,1,t1);
    LGKM8; BAR; LGKM0; SB0; PRIO1; MMQ(0,0); PRIO0; BAR;
    RDB(0,1);
    BAR; LGKM0; SB0; PRIO1; MMQ(0,1); PRIO0; BAR;
    RDA(0,1);
    ISSUE(1,0,0,t2); ISSUE(1,0,1,t2);
    BAR; LGKM0; SB0; PRIO1; MMQ(1,0); PRIO0; BAR;
    ISSUE(0,0,0,t2);
    BAR; PRIO1; MMQ(1,1); PRIO0; VM6; BAR;

    // ---- tile 2i+1 (buf1) ----
    RDA(65536,0); RDB(65536,0);
    ISSUE(0,0,1,t2);
    LGKM8; BAR; LGKM0; SB0; PRIO1; MMQ(0,0); PRIO0; BAR;
    RDB(65536,1);
    BAR; LGKM0; SB0; PRIO1; MMQ(0,1); PRIO0; BAR;
    RDA(65536,1);
    ISSUE(1,1,0,t3); ISSUE(1,1,1,t3);
    BAR; LGKM0; SB0; PRIO1; MMQ(1,0); PRIO0; BAR;
    ISSUE(0,1,0,t3);
    BAR; PRIO1; MMQ(1,1); PRIO0; VM6; BAR;
  }

  // Epilogue: tile 24 (buf0), fully landed by final VM6+BAR.
  RDA(0,0); RDB(0,0); RDB(0,1);
  MMQ(0,0); MMQ(0,1);
  RDA(0,1);
  MMQ(1,0); MMQ(1,1);

  // Fused reduction: sum of squares of the 256x256 tile (layout-free).
  float p = 0.f;
  #pragma unroll
  for (int f = 0; f < 8; f++)
    #pragma unroll
    for (int e = 0; e < 16; e++)
      p = fmaf(acc[f][e], acc[f][e], p);
  #pragma unroll
  for (int off = 32; off; off >>= 1) p += __shfl_down(p, off);
  __syncthreads();
  float* red = (float*)lds;
  if (l == 0) red[w] = p;
  __syncthreads();
  if (tid == 0){
    float sum = red[0]+red[1]+red[2]+red[3]+red[4]+red[5]+red[6]+red[7];
    atomicAdd(&accbuf[which], wgt * sum);
  }
}

__global__ void k_fin(const float* __restrict__ acc, float* __restrict__ out){
  // / (8*1024*1024) and / 2^20 (both operands pre-scaled by 2^5)
  out[0] = (acc[0] - 2.0f*acc[1]) * 1.1368683772161603e-13f;   // 2^-43
}

extern "C" void kernel_launch(void* const* d_in, const int* in_sizes, int n_in,
                              void* d_out, int out_size, void* d_ws, size_t ws_size,
                              hipStream_t stream){
  const float* fs = (const float*)d_in[0];
  const float* ft = (const float*)d_in[1];
  float* out = (float*)d_out;
  float* accbuf = (float*)d_ws;
  char* Sn = (char*)d_ws + 256;
  char* Tn = Sn + (size_t)NB*NC*ROWB8;   // 2 x 26.2 MB of ws

  k_norm<<<dim3(NGRID), dim3(256), 0, stream>>>(fs, ft, Sn, Tn, accbuf);
  k_gemm<<<dim3(208), dim3(512), 0, stream>>>(Sn, Tn, accbuf);
  k_fin<<<1, 1, 0, stream>>>(accbuf, out);
}